// Round 1
// baseline (622.507 us; speedup 1.0000x reference)
//
#include <hip/hip_runtime.h>
#include <hip/hip_bf16.h>
#include <math.h>

#define N_NODES 20000
#define N_EDGES 320000
#define N_GRAPHS 8

__device__ __forceinline__ float leaky02(float x) { return x > 0.f ? x : 0.2f * x; }

// ---------------- encoder: x[N,5] -> relu -> [N,64] -> relu -> [N,128] ----------------
__global__ void encoder_kernel(const float* __restrict__ x,
                               const float* __restrict__ w1, const float* __restrict__ b1,
                               const float* __restrict__ w2, const float* __restrict__ b2,
                               float* __restrict__ out) {
    const int n0 = blockIdx.x * 8;
    const int tid = threadIdx.x; // 128
    __shared__ float s_x[8][5];
    __shared__ float s_h1[8][64];
    if (tid < 40) s_x[tid / 5][tid % 5] = x[(size_t)(n0 + tid / 5) * 5 + (tid % 5)];
    __syncthreads();
    if (tid < 64) {
        #pragma unroll
        for (int n = 0; n < 8; ++n) {
            float a = b1[tid];
            #pragma unroll
            for (int k = 0; k < 5; ++k) a += s_x[n][k] * w1[k * 64 + tid];
            s_h1[n][tid] = fmaxf(a, 0.f);
        }
    }
    __syncthreads();
    float acc[8];
    #pragma unroll
    for (int n = 0; n < 8; ++n) acc[n] = b2[tid];
    for (int k = 0; k < 64; ++k) {
        float wv = w2[k * 128 + tid];
        #pragma unroll
        for (int n = 0; n < 8; ++n) acc[n] += s_h1[n][k] * wv;
    }
    #pragma unroll
    for (int n = 0; n < 8; ++n) out[(size_t)(n0 + n) * 128 + tid] = fmaxf(acc[n], 0.f);
}

// ---------------- edge_attr mean (sum; divided later) ----------------
__global__ void ea_sum_kernel(const float* __restrict__ ea, float* __restrict__ ea_sum) {
    const int tid = threadIdx.x;
    float a0 = 0, a1 = 0, a2 = 0, a3 = 0;
    for (int i = blockIdx.x * blockDim.x + tid; i < N_EDGES; i += gridDim.x * blockDim.x) {
        float4 v = ((const float4*)ea)[i];
        a0 += v.x; a1 += v.y; a2 += v.z; a3 += v.w;
    }
    #pragma unroll
    for (int off = 32; off; off >>= 1) {
        a0 += __shfl_down(a0, off, 64);
        a1 += __shfl_down(a1, off, 64);
        a2 += __shfl_down(a2, off, 64);
        a3 += __shfl_down(a3, off, 64);
    }
    __shared__ float s[4][4];
    const int wave = tid >> 6, lane = tid & 63;
    if (lane == 0) { s[wave][0] = a0; s[wave][1] = a1; s[wave][2] = a2; s[wave][3] = a3; }
    __syncthreads();
    if (tid < 4) {
        float t = s[0][tid] + s[1][tid] + s[2][tid] + s[3][tid];
        atomicAdd(&ea_sum[tid], t);
    }
}

// ---------------- CSR by dst ----------------
__global__ void count_kernel(const int* __restrict__ dst, int* __restrict__ cnt) {
    int i = blockIdx.x * 256 + threadIdx.x;
    if (i < N_EDGES) atomicAdd(&cnt[dst[i]], 1);
}

__global__ void scan_kernel(const int* __restrict__ cnt, int* __restrict__ row_ptr) {
    // 1 block, 1024 threads, 20 items each (20480 >= 20000)
    __shared__ int s_sum[1024];
    const int tid = threadIdx.x;
    int local[20];
    int run = 0;
    const int base = tid * 20;
    #pragma unroll
    for (int i = 0; i < 20; ++i) {
        int idx = base + i;
        int v = (idx < N_NODES) ? cnt[idx] : 0;
        run += v;
        local[i] = run; // inclusive within thread
    }
    s_sum[tid] = run;
    __syncthreads();
    for (int off = 1; off < 1024; off <<= 1) {
        int v = (tid >= off) ? s_sum[tid - off] : 0;
        __syncthreads();
        s_sum[tid] += v;
        __syncthreads();
    }
    const int prev = (tid > 0) ? s_sum[tid - 1] : 0;
    #pragma unroll
    for (int i = 0; i < 20; ++i) {
        int idx = base + i;
        if (idx < N_NODES) row_ptr[idx + 1] = prev + local[i];
    }
    if (tid == 0) row_ptr[0] = 0;
}

__global__ void scatter_kernel(const int* __restrict__ dst, const int* __restrict__ row_ptr,
                               int* __restrict__ cur, int* __restrict__ eid) {
    int i = blockIdx.x * 256 + threadIdx.x;
    if (i < N_EDGES) {
        int d = dst[i];
        int p = atomicAdd(&cur[d], 1);
        eid[row_ptr[d] + p] = i;
    }
}

// ---------------- per-layer tiny precompute: v[k][h], loop a_e ----------------
template<int H>
__global__ void vtab_kernel(const float* __restrict__ We, const float* __restrict__ att_edge,
                            const float* __restrict__ ea_sum,
                            float* __restrict__ vtab, float* __restrict__ lpae) {
    const int tid = threadIdx.x;
    __shared__ float s_v[4][4];
    if (tid < 4 * H) {
        const int k = tid / H, h = tid % H;
        float v = 0.f;
        for (int c = 0; c < 64; ++c) v += We[k * (H * 64) + h * 64 + c] * att_edge[h * 64 + c];
        vtab[k * 4 + h] = v;
        s_v[k][h] = v;
    }
    __syncthreads();
    if (tid < H) {
        const float inv = 1.0f / (float)N_EDGES;
        float l = 0.f;
        #pragma unroll
        for (int k = 0; k < 4; ++k) l += ea_sum[k] * inv * s_v[k][tid];
        lpae[tid] = l;
    }
}

// ---------------- GEMM: Y[N,HC] = X[N,K] @ W[K,HC] ----------------
template<int HC>
__global__ void gemm_kernel(const float* __restrict__ X, const float* __restrict__ W,
                            float* __restrict__ Y, int K) {
    constexpr int CPT = HC / 64; // cols per thread (4 or 1)
    constexpr int TK = 32, BM = 32;
    __shared__ float ldsW[TK][HC];
    __shared__ float ldsX[TK][BM]; // transposed
    const int tid = threadIdx.x;
    const int tx = tid & 63, ty = tid >> 6;
    const int n0 = blockIdx.x * BM;
    float acc[8][CPT];
    #pragma unroll
    for (int n = 0; n < 8; ++n)
        #pragma unroll
        for (int c = 0; c < CPT; ++c) acc[n][c] = 0.f;

    for (int k0 = 0; k0 < K; k0 += TK) {
        constexpr int WF4 = TK * HC / 4;
        for (int i = tid; i < WF4; i += 256) {
            int r = i / (HC / 4), c4 = i % (HC / 4);
            ((float4*)&ldsW[r][0])[c4] = ((const float4*)W)[(size_t)(k0 + r) * (HC / 4) + c4];
        }
        {
            int r = tid / 8;   // 0..31
            int kq = tid % 8;  // 0..7
            float4 v = ((const float4*)X)[((size_t)(n0 + r) * K + k0) / 4 + kq];
            ldsX[kq * 4 + 0][r] = v.x;
            ldsX[kq * 4 + 1][r] = v.y;
            ldsX[kq * 4 + 2][r] = v.z;
            ldsX[kq * 4 + 3][r] = v.w;
        }
        __syncthreads();
        #pragma unroll
        for (int kk = 0; kk < TK; ++kk) {
            float wv[CPT];
            if (CPT == 4) {
                float4 wq = *(const float4*)&ldsW[kk][tx * 4];
                wv[0] = wq.x; wv[1] = wq.y; wv[2] = wq.z; wv[3] = wq.w;
            } else {
                wv[0] = ldsW[kk][tx];
            }
            float xv[8];
            *(float4*)&xv[0] = *(const float4*)&ldsX[kk][ty * 8];
            *(float4*)&xv[4] = *(const float4*)&ldsX[kk][ty * 8 + 4];
            #pragma unroll
            for (int n = 0; n < 8; ++n)
                #pragma unroll
                for (int c = 0; c < CPT; ++c) acc[n][c] += xv[n] * wv[c];
        }
        __syncthreads();
    }
    #pragma unroll
    for (int n = 0; n < 8; ++n) {
        int node = n0 + ty * 8 + n;
        if (CPT == 4) {
            float4 o = make_float4(acc[n][0], acc[n][1], acc[n][2], acc[n][3]);
            *(float4*)&Y[(size_t)node * HC + tx * 4] = o;
        } else {
            Y[(size_t)node * HC + tx] = acc[n][0];
        }
    }
}

// ---------------- attention scalars a_s,a_d [N,H] ----------------
template<int H, int HC>
__global__ void att_kernel(const float* __restrict__ hh,
                           const float* __restrict__ asrc, const float* __restrict__ adst,
                           float* __restrict__ a_s, float* __restrict__ a_d) {
    const int n = blockIdx.x;
    const int tid = threadIdx.x; // HC
    float v = hh[(size_t)n * HC + tid];
    float ps = v * asrc[tid];
    float pd = v * adst[tid];
    #pragma unroll
    for (int off = 32; off; off >>= 1) {
        ps += __shfl_down(ps, off, 64);
        pd += __shfl_down(pd, off, 64);
    }
    if ((tid & 63) == 0) {
        a_s[(size_t)n * H + (tid >> 6)] = ps;
        a_d[(size_t)n * H + (tid >> 6)] = pd;
    }
}

// ---------------- GAT aggregation: one block per dst node ----------------
template<int H, int HC, bool ELU>
__global__ void agg_kernel(const float* __restrict__ hh,
                           const float* __restrict__ a_s, const float* __restrict__ a_d,
                           const float* __restrict__ vtab, const float* __restrict__ lpae,
                           const float* __restrict__ ea,
                           const int* __restrict__ srcs,
                           const int* __restrict__ row_ptr, const int* __restrict__ eids,
                           const float* __restrict__ bias,
                           float* __restrict__ out) {
    constexpr int C = HC / H;
    const int d = blockIdx.x;
    const int tid = threadIdx.x; // 256
    __shared__ float s_m[H];
    __shared__ float s_z[H];
    __shared__ float s_w[64][H];
    __shared__ int s_src[64];
    __shared__ float s_red[4][H];

    const int base = row_ptr[d], end = row_ptr[d + 1];

    float vt[4][H];
    #pragma unroll
    for (int k = 0; k < 4; ++k)
        #pragma unroll
        for (int h = 0; h < H; ++h) vt[k][h] = vtab[k * 4 + h];

    float add_[H], lloop[H];
    #pragma unroll
    for (int h = 0; h < H; ++h) add_[h] = a_d[(size_t)d * H + h];
    #pragma unroll
    for (int h = 0; h < H; ++h)
        lloop[h] = leaky02(a_s[(size_t)d * H + h] + add_[h] + lpae[h]);

    // pass 1: segment max (self-loop as init, identical on all threads)
    float lmax[H];
    #pragma unroll
    for (int h = 0; h < H; ++h) lmax[h] = lloop[h];
    for (int e = base + tid; e < end; e += 256) {
        int ei = eids[e];
        int s = srcs[ei];
        float4 eav = ((const float4*)ea)[ei];
        #pragma unroll
        for (int h = 0; h < H; ++h) {
            float ae = eav.x * vt[0][h] + eav.y * vt[1][h] + eav.z * vt[2][h] + eav.w * vt[3][h];
            float l = leaky02(a_s[(size_t)s * H + h] + add_[h] + ae);
            lmax[h] = fmaxf(lmax[h], l);
        }
    }
    #pragma unroll
    for (int h = 0; h < H; ++h)
        #pragma unroll
        for (int off = 32; off; off >>= 1)
            lmax[h] = fmaxf(lmax[h], __shfl_down(lmax[h], off, 64));
    const int wave = tid >> 6, lane = tid & 63;
    if (lane == 0) {
        #pragma unroll
        for (int h = 0; h < H; ++h) s_red[wave][h] = lmax[h];
    }
    __syncthreads();
    if (tid < H) {
        float m = fmaxf(fmaxf(s_red[0][tid], s_red[1][tid]), fmaxf(s_red[2][tid], s_red[3][tid]));
        s_m[tid] = m;
        s_z[tid] = expf(lloop[tid] - m); // self-loop weight seeds z
    }
    __syncthreads();
    float m_[H];
    #pragma unroll
    for (int h = 0; h < H; ++h) m_[h] = s_m[h];

    const int j = tid;
    const int hj = (H == 1) ? 0 : (j / C);
    float acc = 0.f;
    float wl[H];
    #pragma unroll
    for (int h = 0; h < H; ++h) wl[h] = expf(lloop[h] - m_[h]);
    if (tid < HC) acc = wl[hj] * hh[(size_t)d * HC + j]; // self-loop message

    const int deg = end - base;
    for (int c0 = 0; c0 < deg; c0 += 64) {
        const int nc = min(64, deg - c0);
        if (tid < nc) {
            int ei = eids[base + c0 + tid];
            int s = srcs[ei];
            s_src[tid] = s;
            float4 eav = ((const float4*)ea)[ei];
            #pragma unroll
            for (int h = 0; h < H; ++h) {
                float ae = eav.x * vt[0][h] + eav.y * vt[1][h] + eav.z * vt[2][h] + eav.w * vt[3][h];
                float l = leaky02(a_s[(size_t)s * H + h] + add_[h] + ae);
                float w = expf(l - m_[h]);
                s_w[tid][h] = w;
                atomicAdd(&s_z[h], w);
            }
        }
        __syncthreads();
        if (tid < HC) {
            for (int t = 0; t < nc; ++t)
                acc += s_w[t][hj] * hh[(size_t)s_src[t] * HC + j];
        }
        __syncthreads();
    }
    if (tid < HC) {
        float z = s_z[hj] + 1e-16f;
        float o = acc / z + bias[j];
        if (ELU) o = (o > 0.f) ? o : (expf(o) - 1.f);
        out[(size_t)d * HC + j] = o;
    }
}

// ---------------- global mean pool (hierarchical) ----------------
__global__ void pool_kernel(const float* __restrict__ h3, const int* __restrict__ batch,
                            float* __restrict__ psum, float* __restrict__ pcnt) {
    __shared__ float s_acc[8][64];
    __shared__ float s_cnt[8];
    const int tid = threadIdx.x; // 256
    for (int i = tid; i < 512; i += 256) s_acc[i >> 6][i & 63] = 0.f;
    if (tid < 8) s_cnt[tid] = 0.f;
    __syncthreads();
    const int col = tid & 63, nl = tid >> 6;
    const int n0 = blockIdx.x * 64;
    for (int nn = nl; nn < 64; nn += 4) {
        int n = n0 + nn;
        if (n < N_NODES) {
            int b = batch[n];
            atomicAdd(&s_acc[b][col], h3[(size_t)n * 64 + col]);
            if (col == 0) atomicAdd(&s_cnt[b], 1.0f);
        }
    }
    __syncthreads();
    for (int i = tid; i < 512; i += 256) {
        float v = s_acc[i >> 6][i & 63];
        if (v != 0.f) atomicAdd(&psum[i], v);
    }
    if (tid < 8 && s_cnt[tid] > 0.f) atomicAdd(&pcnt[tid], s_cnt[tid]);
}

// ---------------- head: g -> p1 -> static_features -> scores ----------------
__global__ void head_kernel(const float* __restrict__ psum, const float* __restrict__ pcnt,
                            const float* __restrict__ w1, const float* __restrict__ b1,
                            const float* __restrict__ w2, const float* __restrict__ b2,
                            const float* __restrict__ vw, const float* __restrict__ vb,
                            float* __restrict__ out) {
    __shared__ float s_g[8][64];
    __shared__ float s_p1[8][128];
    __shared__ float s_sf[8][768];
    const int tid = threadIdx.x; // 768
    for (int i = tid; i < 512; i += 768) {
        int b = i >> 6;
        float c = pcnt[b];
        c = (c < 1.f) ? 1.f : c;
        s_g[b][i & 63] = psum[i] / c;
    }
    __syncthreads();
    for (int i = tid; i < 1024; i += 768) {
        int b = i >> 7, j = i & 127;
        float a = b1[j];
        for (int k = 0; k < 64; ++k) a += s_g[b][k] * w1[k * 128 + j];
        s_p1[b][j] = fmaxf(a, 0.f);
    }
    __syncthreads();
    for (int b = 0; b < 8; ++b) {
        float a = b2[tid];
        for (int k = 0; k < 128; ++k) a += s_p1[b][k] * w2[k * 768 + tid];
        s_sf[b][tid] = a;
        out[b * 768 + tid] = a;
    }
    __syncthreads();
    if (tid < 40) {
        int b = tid / 5, v = tid % 5;
        float a = vb[v];
        for (int k = 0; k < 768; ++k) a += s_sf[b][k] * vw[k * 5 + v];
        out[6144 + b * 5 + v] = 1.f / (1.f + expf(-a));
    }
}

extern "C" void kernel_launch(void* const* d_in, const int* in_sizes, int n_in,
                              void* d_out, int out_size, void* d_ws, size_t ws_size,
                              hipStream_t stream) {
    const float* x       = (const float*)d_in[0];
    const int*   eidx    = (const int*)d_in[1];
    const float* ea      = (const float*)d_in[2];
    const int*   batch   = (const int*)d_in[3];
    const float* enc_w1  = (const float*)d_in[4];
    const float* enc_b1  = (const float*)d_in[5];
    const float* enc_w2  = (const float*)d_in[6];
    const float* enc_b2  = (const float*)d_in[7];
    const float* g1_w    = (const float*)d_in[8];
    const float* g1_asrc = (const float*)d_in[9];
    const float* g1_adst = (const float*)d_in[10];
    const float* g1_we   = (const float*)d_in[11];
    const float* g1_ae   = (const float*)d_in[12];
    const float* g1_b    = (const float*)d_in[13];
    const float* g2_w    = (const float*)d_in[14];
    const float* g2_asrc = (const float*)d_in[15];
    const float* g2_adst = (const float*)d_in[16];
    const float* g2_we   = (const float*)d_in[17];
    const float* g2_ae   = (const float*)d_in[18];
    const float* g2_b    = (const float*)d_in[19];
    const float* g3_w    = (const float*)d_in[20];
    const float* g3_asrc = (const float*)d_in[21];
    const float* g3_adst = (const float*)d_in[22];
    const float* g3_we   = (const float*)d_in[23];
    const float* g3_ae   = (const float*)d_in[24];
    const float* g3_b    = (const float*)d_in[25];
    const float* pw1     = (const float*)d_in[26];
    const float* pb1     = (const float*)d_in[27];
    const float* pw2     = (const float*)d_in[28];
    const float* pb2     = (const float*)d_in[29];
    const float* vw      = (const float*)d_in[30];
    const float* vb      = (const float*)d_in[31];

    const int* src = eidx;
    const int* dst = eidx + N_EDGES;

    float* fws = (float*)d_ws;
    size_t o = 0;
    float* bufA = fws + o; o += (size_t)N_NODES * 256;
    float* bufB = fws + o; o += (size_t)N_NODES * 256;
    float* hhb  = fws + o; o += (size_t)N_NODES * 256;
    float* asb  = fws + o; o += (size_t)N_NODES * 4;
    float* adb  = fws + o; o += (size_t)N_NODES * 4;
    float* zreg = fws + o;            // ea_sum[4] psum[512] pcnt[8]
    float* ea_sum = zreg;
    float* psum   = zreg + 4;
    float* pcnt   = zreg + 516;
    o += 524;
    float* vtab = fws + o; o += 16;
    float* lpae = fws + o; o += 4;
    int* icnt = (int*)(fws + o);
    int* icur = icnt + N_NODES;
    int* irow = icur + N_NODES;          // N+1
    int* ieid = irow + N_NODES + 4;      // E

    hipMemsetAsync(zreg, 0, 524 * sizeof(float), stream);
    hipMemsetAsync(icnt, 0, 2 * N_NODES * sizeof(int), stream);

    ea_sum_kernel<<<256, 256, 0, stream>>>(ea, ea_sum);
    encoder_kernel<<<N_NODES / 8, 128, 0, stream>>>(x, enc_w1, enc_b1, enc_w2, enc_b2, bufA);
    count_kernel<<<(N_EDGES + 255) / 256, 256, 0, stream>>>(dst, icnt);
    scan_kernel<<<1, 1024, 0, stream>>>(icnt, irow);
    scatter_kernel<<<(N_EDGES + 255) / 256, 256, 0, stream>>>(dst, irow, icur, ieid);

    // layer 1: K=128 -> HC=256, ELU
    vtab_kernel<4><<<1, 64, 0, stream>>>(g1_we, g1_ae, ea_sum, vtab, lpae);
    gemm_kernel<256><<<N_NODES / 32, 256, 0, stream>>>(bufA, g1_w, hhb, 128);
    att_kernel<4, 256><<<N_NODES, 256, 0, stream>>>(hhb, g1_asrc, g1_adst, asb, adb);
    agg_kernel<4, 256, true><<<N_NODES, 256, 0, stream>>>(hhb, asb, adb, vtab, lpae, ea, src, irow, ieid, g1_b, bufB);

    // layer 2: K=256 -> HC=256, ELU
    vtab_kernel<4><<<1, 64, 0, stream>>>(g2_we, g2_ae, ea_sum, vtab, lpae);
    gemm_kernel<256><<<N_NODES / 32, 256, 0, stream>>>(bufB, g2_w, hhb, 256);
    att_kernel<4, 256><<<N_NODES, 256, 0, stream>>>(hhb, g2_asrc, g2_adst, asb, adb);
    agg_kernel<4, 256, true><<<N_NODES, 256, 0, stream>>>(hhb, asb, adb, vtab, lpae, ea, src, irow, ieid, g2_b, bufA);

    // layer 3: K=256 -> HC=64, heads=1, no ELU
    vtab_kernel<1><<<1, 64, 0, stream>>>(g3_we, g3_ae, ea_sum, vtab, lpae);
    gemm_kernel<64><<<N_NODES / 32, 256, 0, stream>>>(bufA, g3_w, hhb, 256);
    att_kernel<1, 64><<<N_NODES, 64, 0, stream>>>(hhb, g3_asrc, g3_adst, asb, adb);
    agg_kernel<1, 64, false><<<N_NODES, 256, 0, stream>>>(hhb, asb, adb, vtab, lpae, ea, src, irow, ieid, g3_b, bufB);

    pool_kernel<<<(N_NODES + 63) / 64, 256, 0, stream>>>(bufB, batch, psum, pcnt);
    head_kernel<<<1, 768, 0, stream>>>(psum, pcnt, pw1, pb1, pw2, pb2, vw, vb, (float*)d_out);
}

// Round 2
// 508.100 us; speedup vs baseline: 1.2252x; 1.2252x over previous
//
#include <hip/hip_runtime.h>
#include <hip/hip_bf16.h>
#include <math.h>

#define N_NODES 20000
#define N_EDGES 320000
#define N_GRAPHS 8

__device__ __forceinline__ float leaky02(float x) { return x > 0.f ? x : 0.2f * x; }

// ---------------- encoder: x[N,5] -> relu -> [N,64] -> relu -> [N,128] ----------------
__global__ void encoder_kernel(const float* __restrict__ x,
                               const float* __restrict__ w1, const float* __restrict__ b1,
                               const float* __restrict__ w2, const float* __restrict__ b2,
                               float* __restrict__ out) {
    const int n0 = blockIdx.x * 8;
    const int tid = threadIdx.x; // 128
    __shared__ float s_x[8][5];
    __shared__ float s_h1[8][64];
    if (tid < 40) s_x[tid / 5][tid % 5] = x[(size_t)(n0 + tid / 5) * 5 + (tid % 5)];
    __syncthreads();
    if (tid < 64) {
        #pragma unroll
        for (int n = 0; n < 8; ++n) {
            float a = b1[tid];
            #pragma unroll
            for (int k = 0; k < 5; ++k) a += s_x[n][k] * w1[k * 64 + tid];
            s_h1[n][tid] = fmaxf(a, 0.f);
        }
    }
    __syncthreads();
    float acc[8];
    #pragma unroll
    for (int n = 0; n < 8; ++n) acc[n] = b2[tid];
    for (int k = 0; k < 64; ++k) {
        float wv = w2[k * 128 + tid];
        #pragma unroll
        for (int n = 0; n < 8; ++n) acc[n] += s_h1[n][k] * wv;
    }
    #pragma unroll
    for (int n = 0; n < 8; ++n) out[(size_t)(n0 + n) * 128 + tid] = fmaxf(acc[n], 0.f);
}

// ---------------- edge_attr mean (sum; divided later) ----------------
__global__ void ea_sum_kernel(const float* __restrict__ ea, float* __restrict__ ea_sum) {
    const int tid = threadIdx.x;
    float a0 = 0, a1 = 0, a2 = 0, a3 = 0;
    for (int i = blockIdx.x * blockDim.x + tid; i < N_EDGES; i += gridDim.x * blockDim.x) {
        float4 v = ((const float4*)ea)[i];
        a0 += v.x; a1 += v.y; a2 += v.z; a3 += v.w;
    }
    #pragma unroll
    for (int off = 32; off; off >>= 1) {
        a0 += __shfl_down(a0, off, 64);
        a1 += __shfl_down(a1, off, 64);
        a2 += __shfl_down(a2, off, 64);
        a3 += __shfl_down(a3, off, 64);
    }
    __shared__ float s[4][4];
    const int wave = tid >> 6, lane = tid & 63;
    if (lane == 0) { s[wave][0] = a0; s[wave][1] = a1; s[wave][2] = a2; s[wave][3] = a3; }
    __syncthreads();
    if (tid < 4) {
        float t = s[0][tid] + s[1][tid] + s[2][tid] + s[3][tid];
        atomicAdd(&ea_sum[tid], t);
    }
}

// ---------------- CSR by dst ----------------
__global__ void count_kernel(const int* __restrict__ dst, int* __restrict__ cnt) {
    int i = blockIdx.x * 256 + threadIdx.x;
    if (i < N_EDGES) atomicAdd(&cnt[dst[i]], 1);
}

__global__ void scan_kernel(const int* __restrict__ cnt, int* __restrict__ row_ptr) {
    // 1 block, 1024 threads, 20 items each (20480 >= 20000)
    __shared__ int s_sum[1024];
    const int tid = threadIdx.x;
    int local[20];
    int run = 0;
    const int base = tid * 20;
    #pragma unroll
    for (int i = 0; i < 20; ++i) {
        int idx = base + i;
        int v = (idx < N_NODES) ? cnt[idx] : 0;
        run += v;
        local[i] = run; // inclusive within thread
    }
    s_sum[tid] = run;
    __syncthreads();
    for (int off = 1; off < 1024; off <<= 1) {
        int v = (tid >= off) ? s_sum[tid - off] : 0;
        __syncthreads();
        s_sum[tid] += v;
        __syncthreads();
    }
    const int prev = (tid > 0) ? s_sum[tid - 1] : 0;
    #pragma unroll
    for (int i = 0; i < 20; ++i) {
        int idx = base + i;
        if (idx < N_NODES) row_ptr[idx + 1] = prev + local[i];
    }
    if (tid == 0) row_ptr[0] = 0;
}

__global__ void scatter_kernel(const int* __restrict__ dst, const int* __restrict__ row_ptr,
                               int* __restrict__ cur, int* __restrict__ eid) {
    int i = blockIdx.x * 256 + threadIdx.x;
    if (i < N_EDGES) {
        int d = dst[i];
        int p = atomicAdd(&cur[d], 1);
        eid[row_ptr[d] + p] = i;
    }
}

// build CSR-ordered src + edge_attr streams (coalesced reads for all 6 agg passes)
__global__ void csr_gather_kernel(const int* __restrict__ srcs, const float* __restrict__ ea,
                                  const int* __restrict__ eids,
                                  int* __restrict__ csr_src, float* __restrict__ csr_ea) {
    int e = blockIdx.x * 256 + threadIdx.x;
    if (e < N_EDGES) {
        int ei = eids[e];
        csr_src[e] = srcs[ei];
        ((float4*)csr_ea)[e] = ((const float4*)ea)[ei];
    }
}

// ---------------- per-layer tiny precompute: v[k][h], loop a_e ----------------
template<int H>
__global__ void vtab_kernel(const float* __restrict__ We, const float* __restrict__ att_edge,
                            const float* __restrict__ ea_sum,
                            float* __restrict__ vtab, float* __restrict__ lpae) {
    const int tid = threadIdx.x;
    __shared__ float s_v[4][4];
    if (tid < 4 * H) {
        const int k = tid / H, h = tid % H;
        float v = 0.f;
        for (int c = 0; c < 64; ++c) v += We[k * (H * 64) + h * 64 + c] * att_edge[h * 64 + c];
        vtab[k * 4 + h] = v;
        s_v[k][h] = v;
    }
    __syncthreads();
    if (tid < H) {
        const float inv = 1.0f / (float)N_EDGES;
        float l = 0.f;
        #pragma unroll
        for (int k = 0; k < 4; ++k) l += ea_sum[k] * inv * s_v[k][tid];
        lpae[tid] = l;
    }
}

// ---------------- GEMM: Y[N,HC] = X[N,K] @ W[K,HC] ----------------
template<int HC>
__global__ void gemm_kernel(const float* __restrict__ X, const float* __restrict__ W,
                            float* __restrict__ Y, int K) {
    constexpr int CPT = HC / 64; // cols per thread (4 or 1)
    constexpr int TK = 32, BM = 32;
    __shared__ float ldsW[TK][HC];
    __shared__ float ldsX[TK][BM]; // transposed
    const int tid = threadIdx.x;
    const int tx = tid & 63, ty = tid >> 6;
    const int n0 = blockIdx.x * BM;
    float acc[8][CPT];
    #pragma unroll
    for (int n = 0; n < 8; ++n)
        #pragma unroll
        for (int c = 0; c < CPT; ++c) acc[n][c] = 0.f;

    for (int k0 = 0; k0 < K; k0 += TK) {
        constexpr int WF4 = TK * HC / 4;
        for (int i = tid; i < WF4; i += 256) {
            int r = i / (HC / 4), c4 = i % (HC / 4);
            ((float4*)&ldsW[r][0])[c4] = ((const float4*)W)[(size_t)(k0 + r) * (HC / 4) + c4];
        }
        {
            int r = tid / 8;   // 0..31
            int kq = tid % 8;  // 0..7
            float4 v = ((const float4*)X)[((size_t)(n0 + r) * K + k0) / 4 + kq];
            ldsX[kq * 4 + 0][r] = v.x;
            ldsX[kq * 4 + 1][r] = v.y;
            ldsX[kq * 4 + 2][r] = v.z;
            ldsX[kq * 4 + 3][r] = v.w;
        }
        __syncthreads();
        #pragma unroll
        for (int kk = 0; kk < TK; ++kk) {
            float wv[CPT];
            if (CPT == 4) {
                float4 wq = *(const float4*)&ldsW[kk][tx * 4];
                wv[0] = wq.x; wv[1] = wq.y; wv[2] = wq.z; wv[3] = wq.w;
            } else {
                wv[0] = ldsW[kk][tx];
            }
            float xv[8];
            *(float4*)&xv[0] = *(const float4*)&ldsX[kk][ty * 8];
            *(float4*)&xv[4] = *(const float4*)&ldsX[kk][ty * 8 + 4];
            #pragma unroll
            for (int n = 0; n < 8; ++n)
                #pragma unroll
                for (int c = 0; c < CPT; ++c) acc[n][c] += xv[n] * wv[c];
        }
        __syncthreads();
    }
    #pragma unroll
    for (int n = 0; n < 8; ++n) {
        int node = n0 + ty * 8 + n;
        if (CPT == 4) {
            float4 o = make_float4(acc[n][0], acc[n][1], acc[n][2], acc[n][3]);
            *(float4*)&Y[(size_t)node * HC + tx * 4] = o;
        } else {
            Y[(size_t)node * HC + tx] = acc[n][0];
        }
    }
}

// ---------------- attention scalars a_s,a_d [N,H] ----------------
template<int H, int HC>
__global__ void att_kernel(const float* __restrict__ hh,
                           const float* __restrict__ asrc, const float* __restrict__ adst,
                           float* __restrict__ a_s, float* __restrict__ a_d) {
    const int n = blockIdx.x;
    const int tid = threadIdx.x; // HC
    float v = hh[(size_t)n * HC + tid];
    float ps = v * asrc[tid];
    float pd = v * adst[tid];
    #pragma unroll
    for (int off = 32; off; off >>= 1) {
        ps += __shfl_down(ps, off, 64);
        pd += __shfl_down(pd, off, 64);
    }
    if ((tid & 63) == 0) {
        a_s[(size_t)n * H + (tid >> 6)] = ps;
        a_d[(size_t)n * H + (tid >> 6)] = pd;
    }
}

// ---------------- GAT aggregation: one WAVE per dst node, no LDS, no syncs ----------------
template<int H, int HC, bool ELU>
__global__ __launch_bounds__(256) void agg2_kernel(
    const float* __restrict__ hh,
    const float* __restrict__ a_s, const float* __restrict__ a_d,
    const float* __restrict__ vtab, const float* __restrict__ lpae,
    const int* __restrict__ csr_src, const float* __restrict__ csr_ea,
    const int* __restrict__ row_ptr, const float* __restrict__ bias,
    float* __restrict__ out) {
    constexpr int CPT = HC / 64; // cols per lane: 4 (HC=256) or 1 (HC=64)
    const int wave = threadIdx.x >> 6;
    const int lane = threadIdx.x & 63;
    const int d = blockIdx.x * 4 + wave;

    const int base = row_ptr[d], end = row_ptr[d + 1];

    const int colbase = lane * CPT;
    const int hl = (H == 1) ? 0 : (colbase >> 6); // head of this lane's columns

    // vtab for all heads (pass 1 needs every head)
    float vt[4][H];
    #pragma unroll
    for (int k = 0; k < 4; ++k)
        #pragma unroll
        for (int h = 0; h < H; ++h) vt[k][h] = vtab[k * 4 + h];

    float add_[H], lloop[H];
    #pragma unroll
    for (int h = 0; h < H; ++h) add_[h] = a_d[(size_t)d * H + h];
    #pragma unroll
    for (int h = 0; h < H; ++h)
        lloop[h] = leaky02(a_s[(size_t)d * H + h] + add_[h] + lpae[h]);

    // ---- pass 1: segment max (self-loop seeds) ----
    float lmax[H];
    #pragma unroll
    for (int h = 0; h < H; ++h) lmax[h] = lloop[h];
    for (int idx = base + lane; idx < end; idx += 64) {
        int s = csr_src[idx];
        float4 eav = ((const float4*)csr_ea)[idx];
        #pragma unroll
        for (int h = 0; h < H; ++h) {
            float ae = eav.x * vt[0][h] + eav.y * vt[1][h] + eav.z * vt[2][h] + eav.w * vt[3][h];
            float l = leaky02(a_s[(size_t)s * H + h] + add_[h] + ae);
            lmax[h] = fmaxf(lmax[h], l);
        }
    }
    #pragma unroll
    for (int h = 0; h < H; ++h)
        #pragma unroll
        for (int off = 1; off < 64; off <<= 1)
            lmax[h] = fmaxf(lmax[h], __shfl_xor(lmax[h], off, 64));

    // per-lane head-specific constants
    const float mh = lmax[hl];
    const float addh = add_[hl];
    const float vth0 = vt[0][hl], vth1 = vt[1][hl], vth2 = vt[2][hl], vth3 = vt[3][hl];

    // ---- self-loop message ----
    float zacc = __expf(lloop[hl] - mh);
    float acc[CPT];
    {
        const float* rowp = &hh[(size_t)d * HC + colbase];
        #pragma unroll
        for (int c = 0; c < CPT; ++c) acc[c] = zacc * rowp[c];
    }

    // ---- pass 2: weighted gather, unrolled x4 for outstanding loads ----
#define EDGE_STEP(tt) { \
        int s_ = __shfl(my_s, (tt), 64); \
        float ex_ = __shfl(my_ea.x, (tt), 64); \
        float ey_ = __shfl(my_ea.y, (tt), 64); \
        float ez_ = __shfl(my_ea.z, (tt), 64); \
        float ew_ = __shfl(my_ea.w, (tt), 64); \
        float l_ = a_s[(size_t)s_ * H + hl] + addh + ex_ * vth0 + ey_ * vth1 + ez_ * vth2 + ew_ * vth3; \
        l_ = leaky02(l_); \
        float w_ = __expf(l_ - mh); \
        const float* rp_ = &hh[(size_t)s_ * HC + colbase]; \
        if (CPT == 4) { \
            float4 r_ = *(const float4*)rp_; \
            acc[0] += w_ * r_.x; acc[1] += w_ * r_.y; acc[2] += w_ * r_.z; acc[3] += w_ * r_.w; \
        } else { \
            acc[0] += w_ * rp_[0]; \
        } \
        zacc += w_; }

    for (int c0 = base; c0 < end; c0 += 64) {
        const int nc = min(64, end - c0);
        int my_s = 0;
        float4 my_ea = make_float4(0.f, 0.f, 0.f, 0.f);
        if (lane < nc) {
            my_s = csr_src[c0 + lane];
            my_ea = ((const float4*)csr_ea)[c0 + lane];
        }
        int t = 0;
        for (; t + 4 <= nc; t += 4) {
            EDGE_STEP(t)
            EDGE_STEP(t + 1)
            EDGE_STEP(t + 2)
            EDGE_STEP(t + 3)
        }
        for (; t < nc; ++t) {
            EDGE_STEP(t)
        }
    }
#undef EDGE_STEP

    // ---- epilogue ----
    const float invz = 1.f / (zacc + 1e-16f);
    float o[CPT];
    #pragma unroll
    for (int c = 0; c < CPT; ++c) {
        float v = acc[c] * invz + bias[colbase + c];
        if (ELU) v = (v > 0.f) ? v : (__expf(v) - 1.f);
        o[c] = v;
    }
    if (CPT == 4) {
        *(float4*)&out[(size_t)d * HC + colbase] = make_float4(o[0], o[1], o[2], o[3]);
    } else {
        out[(size_t)d * HC + colbase] = o[0];
    }
}

// ---------------- global mean pool (hierarchical) ----------------
__global__ void pool_kernel(const float* __restrict__ h3, const int* __restrict__ batch,
                            float* __restrict__ psum, float* __restrict__ pcnt) {
    __shared__ float s_acc[8][64];
    __shared__ float s_cnt[8];
    const int tid = threadIdx.x; // 256
    for (int i = tid; i < 512; i += 256) s_acc[i >> 6][i & 63] = 0.f;
    if (tid < 8) s_cnt[tid] = 0.f;
    __syncthreads();
    const int col = tid & 63, nl = tid >> 6;
    const int n0 = blockIdx.x * 64;
    for (int nn = nl; nn < 64; nn += 4) {
        int n = n0 + nn;
        if (n < N_NODES) {
            int b = batch[n];
            atomicAdd(&s_acc[b][col], h3[(size_t)n * 64 + col]);
            if (col == 0) atomicAdd(&s_cnt[b], 1.0f);
        }
    }
    __syncthreads();
    for (int i = tid; i < 512; i += 256) {
        float v = s_acc[i >> 6][i & 63];
        if (v != 0.f) atomicAdd(&psum[i], v);
    }
    if (tid < 8 && s_cnt[tid] > 0.f) atomicAdd(&pcnt[tid], s_cnt[tid]);
}

// ---------------- head: g -> p1 -> static_features -> scores ----------------
__global__ void head_kernel(const float* __restrict__ psum, const float* __restrict__ pcnt,
                            const float* __restrict__ w1, const float* __restrict__ b1,
                            const float* __restrict__ w2, const float* __restrict__ b2,
                            const float* __restrict__ vw, const float* __restrict__ vb,
                            float* __restrict__ out) {
    __shared__ float s_g[8][64];
    __shared__ float s_p1[8][128];
    __shared__ float s_sf[8][768];
    const int tid = threadIdx.x; // 768
    for (int i = tid; i < 512; i += 768) {
        int b = i >> 6;
        float c = pcnt[b];
        c = (c < 1.f) ? 1.f : c;
        s_g[b][i & 63] = psum[i] / c;
    }
    __syncthreads();
    for (int i = tid; i < 1024; i += 768) {
        int b = i >> 7, j = i & 127;
        float a = b1[j];
        for (int k = 0; k < 64; ++k) a += s_g[b][k] * w1[k * 128 + j];
        s_p1[b][j] = fmaxf(a, 0.f);
    }
    __syncthreads();
    for (int b = 0; b < 8; ++b) {
        float a = b2[tid];
        for (int k = 0; k < 128; ++k) a += s_p1[b][k] * w2[k * 768 + tid];
        s_sf[b][tid] = a;
        out[b * 768 + tid] = a;
    }
    __syncthreads();
    if (tid < 40) {
        int b = tid / 5, v = tid % 5;
        float a = vb[v];
        for (int k = 0; k < 768; ++k) a += s_sf[b][k] * vw[k * 5 + v];
        out[6144 + b * 5 + v] = 1.f / (1.f + expf(-a));
    }
}

extern "C" void kernel_launch(void* const* d_in, const int* in_sizes, int n_in,
                              void* d_out, int out_size, void* d_ws, size_t ws_size,
                              hipStream_t stream) {
    const float* x       = (const float*)d_in[0];
    const int*   eidx    = (const int*)d_in[1];
    const float* ea      = (const float*)d_in[2];
    const int*   batch   = (const int*)d_in[3];
    const float* enc_w1  = (const float*)d_in[4];
    const float* enc_b1  = (const float*)d_in[5];
    const float* enc_w2  = (const float*)d_in[6];
    const float* enc_b2  = (const float*)d_in[7];
    const float* g1_w    = (const float*)d_in[8];
    const float* g1_asrc = (const float*)d_in[9];
    const float* g1_adst = (const float*)d_in[10];
    const float* g1_we   = (const float*)d_in[11];
    const float* g1_ae   = (const float*)d_in[12];
    const float* g1_b    = (const float*)d_in[13];
    const float* g2_w    = (const float*)d_in[14];
    const float* g2_asrc = (const float*)d_in[15];
    const float* g2_adst = (const float*)d_in[16];
    const float* g2_we   = (const float*)d_in[17];
    const float* g2_ae   = (const float*)d_in[18];
    const float* g2_b    = (const float*)d_in[19];
    const float* g3_w    = (const float*)d_in[20];
    const float* g3_asrc = (const float*)d_in[21];
    const float* g3_adst = (const float*)d_in[22];
    const float* g3_we   = (const float*)d_in[23];
    const float* g3_ae   = (const float*)d_in[24];
    const float* g3_b    = (const float*)d_in[25];
    const float* pw1     = (const float*)d_in[26];
    const float* pb1     = (const float*)d_in[27];
    const float* pw2     = (const float*)d_in[28];
    const float* pb2     = (const float*)d_in[29];
    const float* vw      = (const float*)d_in[30];
    const float* vb      = (const float*)d_in[31];

    const int* src = eidx;
    const int* dst = eidx + N_EDGES;

    float* fws = (float*)d_ws;
    size_t o = 0;
    float* bufA = fws + o; o += (size_t)N_NODES * 256;
    float* hhb  = fws + o; o += (size_t)N_NODES * 256;
    float* asb  = fws + o; o += (size_t)N_NODES * 4;
    float* adb  = fws + o; o += (size_t)N_NODES * 4;
    float* zreg = fws + o;            // ea_sum[4] psum[512] pcnt[8]
    float* ea_sum = zreg;
    float* psum   = zreg + 4;
    float* pcnt   = zreg + 516;
    o += 524;
    float* vtab = fws + o; o += 16;
    float* lpae = fws + o; o += 4;
    int* icnt = (int*)(fws + o);
    int* icur = icnt + N_NODES;
    int* irow = icur + N_NODES;          // N+1
    int* ieid = irow + N_NODES + 4;      // E
    int* csr_src = ieid + N_EDGES;       // E
    o += (size_t)(2 * N_NODES + N_NODES + 4 + 2 * N_EDGES);
    o = (o + 3) & ~(size_t)3;            // 16B align for float4
    float* csr_ea = fws + o; o += (size_t)N_EDGES * 4;

    hipMemsetAsync(zreg, 0, 524 * sizeof(float), stream);
    hipMemsetAsync(icnt, 0, 2 * N_NODES * sizeof(int), stream);

    ea_sum_kernel<<<256, 256, 0, stream>>>(ea, ea_sum);
    encoder_kernel<<<N_NODES / 8, 128, 0, stream>>>(x, enc_w1, enc_b1, enc_w2, enc_b2, bufA);
    count_kernel<<<(N_EDGES + 255) / 256, 256, 0, stream>>>(dst, icnt);
    scan_kernel<<<1, 1024, 0, stream>>>(icnt, irow);
    scatter_kernel<<<(N_EDGES + 255) / 256, 256, 0, stream>>>(dst, irow, icur, ieid);
    csr_gather_kernel<<<(N_EDGES + 255) / 256, 256, 0, stream>>>(src, ea, ieid, csr_src, csr_ea);

    // layer 1: K=128 -> HC=256, ELU    (bufA -> hhb -> bufA)
    vtab_kernel<4><<<1, 64, 0, stream>>>(g1_we, g1_ae, ea_sum, vtab, lpae);
    gemm_kernel<256><<<N_NODES / 32, 256, 0, stream>>>(bufA, g1_w, hhb, 128);
    att_kernel<4, 256><<<N_NODES, 256, 0, stream>>>(hhb, g1_asrc, g1_adst, asb, adb);
    agg2_kernel<4, 256, true><<<N_NODES / 4, 256, 0, stream>>>(hhb, asb, adb, vtab, lpae, csr_src, csr_ea, irow, g1_b, bufA);

    // layer 2: K=256 -> HC=256, ELU
    vtab_kernel<4><<<1, 64, 0, stream>>>(g2_we, g2_ae, ea_sum, vtab, lpae);
    gemm_kernel<256><<<N_NODES / 32, 256, 0, stream>>>(bufA, g2_w, hhb, 256);
    att_kernel<4, 256><<<N_NODES, 256, 0, stream>>>(hhb, g2_asrc, g2_adst, asb, adb);
    agg2_kernel<4, 256, true><<<N_NODES / 4, 256, 0, stream>>>(hhb, asb, adb, vtab, lpae, csr_src, csr_ea, irow, g2_b, bufA);

    // layer 3: K=256 -> HC=64, heads=1, no ELU
    vtab_kernel<1><<<1, 64, 0, stream>>>(g3_we, g3_ae, ea_sum, vtab, lpae);
    gemm_kernel<64><<<N_NODES / 32, 256, 0, stream>>>(bufA, g3_w, hhb, 256);
    att_kernel<1, 64><<<N_NODES, 64, 0, stream>>>(hhb, g3_asrc, g3_adst, asb, adb);
    agg2_kernel<1, 64, false><<<N_NODES / 4, 256, 0, stream>>>(hhb, asb, adb, vtab, lpae, csr_src, csr_ea, irow, g3_b, bufA);

    pool_kernel<<<(N_NODES + 63) / 64, 256, 0, stream>>>(bufA, batch, psum, pcnt);
    head_kernel<<<1, 768, 0, stream>>>(psum, pcnt, pw1, pb1, pw2, pb2, vw, vb, (float*)d_out);
}

// Round 3
// 448.119 us; speedup vs baseline: 1.3892x; 1.1339x over previous
//
#include <hip/hip_runtime.h>
#include <hip/hip_bf16.h>
#include <math.h>

#define N_NODES 20000
#define N_EDGES 320000
#define N_GRAPHS 8

__device__ __forceinline__ float leaky02(float x) { return x > 0.f ? x : 0.2f * x; }
__device__ __forceinline__ float sel4(int hl, float a, float b, float c, float d) {
    return hl < 2 ? (hl == 0 ? a : b) : (hl == 2 ? c : d);
}

// ---------------- encoder: x[N,5] -> relu -> [N,64] -> relu -> [N,128] ----------------
__global__ void encoder_kernel(const float* __restrict__ x,
                               const float* __restrict__ w1, const float* __restrict__ b1,
                               const float* __restrict__ w2, const float* __restrict__ b2,
                               float* __restrict__ out) {
    const int n0 = blockIdx.x * 8;
    const int tid = threadIdx.x; // 128
    __shared__ float s_x[8][5];
    __shared__ float s_h1[8][64];
    if (tid < 40) s_x[tid / 5][tid % 5] = x[(size_t)(n0 + tid / 5) * 5 + (tid % 5)];
    __syncthreads();
    if (tid < 64) {
        #pragma unroll
        for (int n = 0; n < 8; ++n) {
            float a = b1[tid];
            #pragma unroll
            for (int k = 0; k < 5; ++k) a += s_x[n][k] * w1[k * 64 + tid];
            s_h1[n][tid] = fmaxf(a, 0.f);
        }
    }
    __syncthreads();
    float acc[8];
    #pragma unroll
    for (int n = 0; n < 8; ++n) acc[n] = b2[tid];
    for (int k = 0; k < 64; ++k) {
        float wv = w2[k * 128 + tid];
        #pragma unroll
        for (int n = 0; n < 8; ++n) acc[n] += s_h1[n][k] * wv;
    }
    #pragma unroll
    for (int n = 0; n < 8; ++n) out[(size_t)(n0 + n) * 128 + tid] = fmaxf(acc[n], 0.f);
}

// ---------------- edge_attr mean (sum; divided later) ----------------
__global__ void ea_sum_kernel(const float* __restrict__ ea, float* __restrict__ ea_sum) {
    const int tid = threadIdx.x;
    float a0 = 0, a1 = 0, a2 = 0, a3 = 0;
    for (int i = blockIdx.x * blockDim.x + tid; i < N_EDGES; i += gridDim.x * blockDim.x) {
        float4 v = ((const float4*)ea)[i];
        a0 += v.x; a1 += v.y; a2 += v.z; a3 += v.w;
    }
    #pragma unroll
    for (int off = 32; off; off >>= 1) {
        a0 += __shfl_down(a0, off, 64);
        a1 += __shfl_down(a1, off, 64);
        a2 += __shfl_down(a2, off, 64);
        a3 += __shfl_down(a3, off, 64);
    }
    __shared__ float s[4][4];
    const int wave = tid >> 6, lane = tid & 63;
    if (lane == 0) { s[wave][0] = a0; s[wave][1] = a1; s[wave][2] = a2; s[wave][3] = a3; }
    __syncthreads();
    if (tid < 4) {
        float t = s[0][tid] + s[1][tid] + s[2][tid] + s[3][tid];
        atomicAdd(&ea_sum[tid], t);
    }
}

// ---------------- CSR by dst ----------------
__global__ void count_kernel(const int* __restrict__ dst, int* __restrict__ cnt) {
    int i = blockIdx.x * 256 + threadIdx.x;
    if (i < N_EDGES) atomicAdd(&cnt[dst[i]], 1);
}

__global__ void scan_kernel(const int* __restrict__ cnt, int* __restrict__ row_ptr) {
    __shared__ int s_sum[1024];
    const int tid = threadIdx.x;
    int local[20];
    int run = 0;
    const int base = tid * 20;
    #pragma unroll
    for (int i = 0; i < 20; ++i) {
        int idx = base + i;
        int v = (idx < N_NODES) ? cnt[idx] : 0;
        run += v;
        local[i] = run;
    }
    s_sum[tid] = run;
    __syncthreads();
    for (int off = 1; off < 1024; off <<= 1) {
        int v = (tid >= off) ? s_sum[tid - off] : 0;
        __syncthreads();
        s_sum[tid] += v;
        __syncthreads();
    }
    const int prev = (tid > 0) ? s_sum[tid - 1] : 0;
    #pragma unroll
    for (int i = 0; i < 20; ++i) {
        int idx = base + i;
        if (idx < N_NODES) row_ptr[idx + 1] = prev + local[i];
    }
    if (tid == 0) row_ptr[0] = 0;
}

__global__ void scatter_kernel(const int* __restrict__ dst, const int* __restrict__ row_ptr,
                               int* __restrict__ cur, int* __restrict__ eid) {
    int i = blockIdx.x * 256 + threadIdx.x;
    if (i < N_EDGES) {
        int d = dst[i];
        int p = atomicAdd(&cur[d], 1);
        eid[row_ptr[d] + p] = i;
    }
}

__global__ void csr_gather_kernel(const int* __restrict__ srcs, const float* __restrict__ ea,
                                  const int* __restrict__ eids,
                                  int* __restrict__ csr_src, float* __restrict__ csr_ea) {
    int e = blockIdx.x * 256 + threadIdx.x;
    if (e < N_EDGES) {
        int ei = eids[e];
        csr_src[e] = srcs[ei];
        ((float4*)csr_ea)[e] = ((const float4*)ea)[ei];
    }
}

// ---------------- per-layer tiny precompute: v[k][h], loop a_e ----------------
template<int H>
__global__ void vtab_kernel(const float* __restrict__ We, const float* __restrict__ att_edge,
                            const float* __restrict__ ea_sum,
                            float* __restrict__ vtab, float* __restrict__ lpae) {
    const int tid = threadIdx.x;
    __shared__ float s_v[4][4];
    if (tid < 4 * H) {
        const int k = tid / H, h = tid % H;
        float v = 0.f;
        for (int c = 0; c < 64; ++c) v += We[k * (H * 64) + h * 64 + c] * att_edge[h * 64 + c];
        vtab[k * 4 + h] = v;
        s_v[k][h] = v;
    }
    __syncthreads();
    if (tid < H) {
        const float inv = 1.0f / (float)N_EDGES;
        float l = 0.f;
        #pragma unroll
        for (int k = 0; k < 4; ++k) l += ea_sum[k] * inv * s_v[k][tid];
        lpae[tid] = l;
    }
}

// ---------------- GEMM + fused attention scalars ----------------
// Y[N,HC] = X[N,K] @ W[K,HC]; a_s[n,h] = sum_c Y[n,h,c]*asrc[h,c] (same for a_d).
// Block: 32 nodes x BN cols; 256 threads; thread = 8 nodes x CPT cols.
template<int HC, int BN, int H>
__global__ __launch_bounds__(256) void gemm2_kernel(
    const float* __restrict__ X, const float* __restrict__ W,
    const float* __restrict__ asrc, const float* __restrict__ adst,
    float* __restrict__ Y, float* __restrict__ a_s, float* __restrict__ a_d, int K) {
    constexpr int CPT = BN / 64;
    constexpr int TK = 32, BM = 32;
    __shared__ float ldsW[TK][BN];
    __shared__ float ldsX[TK][BM + 4]; // stride 36 floats: 16B-aligned rows, low write conflict
    const int tid = threadIdx.x;
    const int tx = tid & 63, wv = tid >> 6;
    const int n0 = blockIdx.x * BM;
    const int c0 = blockIdx.y * BN;
    float acc[8][CPT];
    #pragma unroll
    for (int n = 0; n < 8; ++n)
        #pragma unroll
        for (int c = 0; c < CPT; ++c) acc[n][c] = 0.f;

    for (int k0 = 0; k0 < K; k0 += TK) {
        constexpr int WF4 = TK * BN / 4;
        #pragma unroll
        for (int i = tid; i < WF4; i += 256) {
            int r = i / (BN / 4), c4 = i % (BN / 4);
            *(float4*)&ldsW[r][c4 * 4] = *(const float4*)&W[(size_t)(k0 + r) * HC + c0 + c4 * 4];
        }
        {
            int r = tid >> 3, kq = tid & 7; // 32 rows x 8 float4
            float4 v = *(const float4*)&X[(size_t)(n0 + r) * K + k0 + kq * 4];
            ldsX[kq * 4 + 0][r] = v.x;
            ldsX[kq * 4 + 1][r] = v.y;
            ldsX[kq * 4 + 2][r] = v.z;
            ldsX[kq * 4 + 3][r] = v.w;
        }
        __syncthreads();
        #pragma unroll
        for (int kk = 0; kk < TK; ++kk) {
            float w0, w1v = 0.f;
            if (CPT == 2) {
                float2 wq = *(const float2*)&ldsW[kk][tx * 2];
                w0 = wq.x; w1v = wq.y;
            } else {
                w0 = ldsW[kk][tx];
            }
            float xv[8];
            *(float4*)&xv[0] = *(const float4*)&ldsX[kk][wv * 8];
            *(float4*)&xv[4] = *(const float4*)&ldsX[kk][wv * 8 + 4];
            #pragma unroll
            for (int n = 0; n < 8; ++n) {
                acc[n][0] += xv[n] * w0;
                if (CPT == 2) acc[n][1] += xv[n] * w1v;
            }
        }
        __syncthreads();
    }

    const int colg = c0 + tx * CPT;
    float ar[CPT], ad[CPT];
    #pragma unroll
    for (int c = 0; c < CPT; ++c) { ar[c] = asrc[colg + c]; ad[c] = adst[colg + c]; }

    #pragma unroll
    for (int n = 0; n < 8; ++n) {
        const int node = n0 + wv * 8 + n;
        if (CPT == 2) {
            *(float2*)&Y[(size_t)node * HC + colg] = make_float2(acc[n][0], acc[n][1]);
        } else {
            Y[(size_t)node * HC + colg] = acc[n][0];
        }
        float p = acc[n][0] * ar[0];
        float q = acc[n][0] * ad[0];
        if (CPT == 2) { p += acc[n][1] * ar[1]; q += acc[n][1] * ad[1]; }
        if (H == 1) {
            #pragma unroll
            for (int off = 1; off < 64; off <<= 1) {
                p += __shfl_xor(p, off, 64);
                q += __shfl_xor(q, off, 64);
            }
            if (tx == 0) { a_s[node] = p; a_d[node] = q; }
        } else {
            #pragma unroll
            for (int off = 1; off < 32; off <<= 1) {
                p += __shfl_xor(p, off, 64);
                q += __shfl_xor(q, off, 64);
            }
            if ((tx & 31) == 0) {
                int head = (c0 >> 6) + (tx >> 5);
                a_s[(size_t)node * H + head] = p;
                a_d[(size_t)node * H + head] = q;
            }
        }
    }
}

// ---------------- GAT aggregation: wave per node, single-pass online softmax ----------------
template<int H, int HC, bool ELU>
__global__ __launch_bounds__(256) void agg3_kernel(
    const float* __restrict__ hh,
    const float* __restrict__ a_s, const float* __restrict__ a_d,
    const float* __restrict__ vtab, const float* __restrict__ lpae,
    const int* __restrict__ csr_src, const float* __restrict__ csr_ea,
    const int* __restrict__ row_ptr, const float* __restrict__ bias,
    float* __restrict__ out) {
    constexpr int CPT = HC / 64;
    const int wave = threadIdx.x >> 6;
    const int lane = threadIdx.x & 63;
    const int d = blockIdx.x * 4 + wave;

    const int base = row_ptr[d], end = row_ptr[d + 1];
    const int colbase = lane * CPT;
    const int hl = (H == 1) ? 0 : (colbase >> 6);

    float vt[4][H];
    #pragma unroll
    for (int k = 0; k < 4; ++k)
        #pragma unroll
        for (int h = 0; h < H; ++h) vt[k][h] = vtab[k * 4 + h];

    float add_[H];
    if (H == 4) {
        float4 t = *(const float4*)&a_d[(size_t)d * 4];
        add_[0] = t.x; add_[1] = t.y; add_[2] = t.z; add_[3] = t.w;
    } else {
        add_[0] = a_d[d];
    }
    float asd_h;
    if (H == 4) asd_h = a_s[(size_t)d * 4 + hl];
    else asd_h = a_s[d];

    // running state: m starts at self-loop logit, z=1, acc = hh[d]
    float mh = leaky02(asd_h + add_[hl] + lpae[hl]);
    float zacc = 1.f;
    float acc[CPT];
    {
        const float* rowp = &hh[(size_t)d * HC + colbase];
        if (CPT == 4) {
            float4 r = *(const float4*)rowp;
            acc[0] = r.x; acc[1] = r.y; acc[2] = r.z; acc[3] = r.w;
        } else {
            acc[0] = rowp[0];
        }
    }

#define EDGE_STEP(tt) { \
        int s_ = __shfl(my_s, (tt), 64); \
        float lt; \
        if (H == 4) { \
            float t0 = __shfl(l0, (tt), 64), t1 = __shfl(l1, (tt), 64); \
            float t2 = __shfl(l2, (tt), 64), t3 = __shfl(l3, (tt), 64); \
            lt = sel4(hl, t0, t1, t2, t3); \
        } else { \
            lt = __shfl(l0, (tt), 64); \
        } \
        float w_ = __expf(lt - mh); \
        const float* rp_ = &hh[(size_t)s_ * HC + colbase]; \
        if (CPT == 4) { \
            float4 r_ = *(const float4*)rp_; \
            acc[0] += w_ * r_.x; acc[1] += w_ * r_.y; acc[2] += w_ * r_.z; acc[3] += w_ * r_.w; \
        } else { \
            acc[0] += w_ * rp_[0]; \
        } \
        zacc += w_; }

    for (int c0 = base; c0 < end; c0 += 64) {
        const int nc = min(64, end - c0);
        int my_s = 0;
        float l0 = -1e30f, l1 = -1e30f, l2 = -1e30f, l3 = -1e30f;
        if (lane < nc) {
            my_s = csr_src[c0 + lane];
            float4 eav = ((const float4*)csr_ea)[c0 + lane];
            if (H == 4) {
                float4 as4 = *(const float4*)&a_s[(size_t)my_s * 4];
                l0 = leaky02(as4.x + add_[0] + eav.x * vt[0][0] + eav.y * vt[1][0] + eav.z * vt[2][0] + eav.w * vt[3][0]);
                l1 = leaky02(as4.y + add_[1] + eav.x * vt[0][1] + eav.y * vt[1][1] + eav.z * vt[2][1] + eav.w * vt[3][1]);
                l2 = leaky02(as4.z + add_[2] + eav.x * vt[0][2] + eav.y * vt[1][2] + eav.z * vt[2][2] + eav.w * vt[3][2]);
                l3 = leaky02(as4.w + add_[3] + eav.x * vt[0][3] + eav.y * vt[1][3] + eav.z * vt[2][3] + eav.w * vt[3][3]);
            } else {
                l0 = leaky02(a_s[my_s] + add_[0] + eav.x * vt[0][0] + eav.y * vt[1][0] + eav.z * vt[2][0] + eav.w * vt[3][0]);
            }
        }
        // chunk maxima per head (result in all lanes)
        float cm0 = l0, cm1 = l1, cm2 = l2, cm3 = l3;
        #pragma unroll
        for (int off = 1; off < 64; off <<= 1) {
            cm0 = fmaxf(cm0, __shfl_xor(cm0, off, 64));
            if (H == 4) {
                cm1 = fmaxf(cm1, __shfl_xor(cm1, off, 64));
                cm2 = fmaxf(cm2, __shfl_xor(cm2, off, 64));
                cm3 = fmaxf(cm3, __shfl_xor(cm3, off, 64));
            }
        }
        float cmh = (H == 4) ? sel4(hl, cm0, cm1, cm2, cm3) : cm0;
        float newm = fmaxf(mh, cmh);
        float sc = __expf(mh - newm);
        zacc *= sc;
        #pragma unroll
        for (int c = 0; c < CPT; ++c) acc[c] *= sc;
        mh = newm;

        int t = 0;
        for (; t + 4 <= nc; t += 4) {
            EDGE_STEP(t)
            EDGE_STEP(t + 1)
            EDGE_STEP(t + 2)
            EDGE_STEP(t + 3)
        }
        for (; t < nc; ++t) {
            EDGE_STEP(t)
        }
    }
#undef EDGE_STEP

    const float invz = 1.f / (zacc + 1e-16f);
    #pragma unroll
    for (int c = 0; c < CPT; ++c) {
        float v = acc[c] * invz + bias[colbase + c];
        if (ELU) v = (v > 0.f) ? v : (__expf(v) - 1.f);
        acc[c] = v;
    }
    if (CPT == 4) {
        *(float4*)&out[(size_t)d * HC + colbase] = make_float4(acc[0], acc[1], acc[2], acc[3]);
    } else {
        out[(size_t)d * HC + colbase] = acc[0];
    }
}

// ---------------- global mean pool (hierarchical) ----------------
__global__ void pool_kernel(const float* __restrict__ h3, const int* __restrict__ batch,
                            float* __restrict__ psum, float* __restrict__ pcnt) {
    __shared__ float s_acc[8][64];
    __shared__ float s_cnt[8];
    const int tid = threadIdx.x; // 256
    for (int i = tid; i < 512; i += 256) s_acc[i >> 6][i & 63] = 0.f;
    if (tid < 8) s_cnt[tid] = 0.f;
    __syncthreads();
    const int col = tid & 63, nl = tid >> 6;
    const int n0 = blockIdx.x * 64;
    for (int nn = nl; nn < 64; nn += 4) {
        int n = n0 + nn;
        if (n < N_NODES) {
            int b = batch[n];
            atomicAdd(&s_acc[b][col], h3[(size_t)n * 64 + col]);
            if (col == 0) atomicAdd(&s_cnt[b], 1.0f);
        }
    }
    __syncthreads();
    for (int i = tid; i < 512; i += 256) {
        float v = s_acc[i >> 6][i & 63];
        if (v != 0.f) atomicAdd(&psum[i], v);
    }
    if (tid < 8 && s_cnt[tid] > 0.f) atomicAdd(&pcnt[tid], s_cnt[tid]);
}

// ---------------- head part 1: static_features (one block = graph x 128-col tile) ----------------
__global__ void head_sf_kernel(const float* __restrict__ psum, const float* __restrict__ pcnt,
                               const float* __restrict__ w1, const float* __restrict__ b1,
                               const float* __restrict__ w2, const float* __restrict__ b2,
                               float* __restrict__ out) {
    const int b = blockIdx.y;
    const int c0 = blockIdx.x * 128;
    const int tid = threadIdx.x; // 128
    __shared__ float s_g[64];
    __shared__ float s_p1[128];
    if (tid < 64) {
        float c = pcnt[b];
        c = (c < 1.f) ? 1.f : c;
        s_g[tid] = psum[b * 64 + tid] / c;
    }
    __syncthreads();
    {
        float a = b1[tid];
        #pragma unroll 8
        for (int k = 0; k < 64; ++k) a += s_g[k] * w1[k * 128 + tid];
        s_p1[tid] = fmaxf(a, 0.f);
    }
    __syncthreads();
    const int col = c0 + tid;
    float a = b2[col];
    #pragma unroll 8
    for (int k = 0; k < 128; ++k) a += s_p1[k] * w2[k * 768 + col];
    out[b * 768 + col] = a;
}

// ---------------- head part 2: vulnerability scores ----------------
__global__ void scores_kernel(const float* __restrict__ sf,
                              const float* __restrict__ vw, const float* __restrict__ vb,
                              float* __restrict__ out) {
    const int b = blockIdx.x;
    const int tid = threadIdx.x; // 256
    const int wave = tid >> 6, lane = tid & 63;
    float part[5] = {0.f, 0.f, 0.f, 0.f, 0.f};
    for (int k = tid; k < 768; k += 256) {
        float s = sf[b * 768 + k];
        #pragma unroll
        for (int v = 0; v < 5; ++v) part[v] += s * vw[k * 5 + v];
    }
    #pragma unroll
    for (int v = 0; v < 5; ++v)
        #pragma unroll
        for (int off = 32; off; off >>= 1) part[v] += __shfl_down(part[v], off, 64);
    __shared__ float sred[4][5];
    if (lane == 0) {
        #pragma unroll
        for (int v = 0; v < 5; ++v) sred[wave][v] = part[v];
    }
    __syncthreads();
    if (tid < 5) {
        float a = vb[tid] + sred[0][tid] + sred[1][tid] + sred[2][tid] + sred[3][tid];
        out[6144 + b * 5 + tid] = 1.f / (1.f + __expf(-a));
    }
}

extern "C" void kernel_launch(void* const* d_in, const int* in_sizes, int n_in,
                              void* d_out, int out_size, void* d_ws, size_t ws_size,
                              hipStream_t stream) {
    const float* x       = (const float*)d_in[0];
    const int*   eidx    = (const int*)d_in[1];
    const float* ea      = (const float*)d_in[2];
    const int*   batch   = (const int*)d_in[3];
    const float* enc_w1  = (const float*)d_in[4];
    const float* enc_b1  = (const float*)d_in[5];
    const float* enc_w2  = (const float*)d_in[6];
    const float* enc_b2  = (const float*)d_in[7];
    const float* g1_w    = (const float*)d_in[8];
    const float* g1_asrc = (const float*)d_in[9];
    const float* g1_adst = (const float*)d_in[10];
    const float* g1_we   = (const float*)d_in[11];
    const float* g1_ae   = (const float*)d_in[12];
    const float* g1_b    = (const float*)d_in[13];
    const float* g2_w    = (const float*)d_in[14];
    const float* g2_asrc = (const float*)d_in[15];
    const float* g2_adst = (const float*)d_in[16];
    const float* g2_we   = (const float*)d_in[17];
    const float* g2_ae   = (const float*)d_in[18];
    const float* g2_b    = (const float*)d_in[19];
    const float* g3_w    = (const float*)d_in[20];
    const float* g3_asrc = (const float*)d_in[21];
    const float* g3_adst = (const float*)d_in[22];
    const float* g3_we   = (const float*)d_in[23];
    const float* g3_ae   = (const float*)d_in[24];
    const float* g3_b    = (const float*)d_in[25];
    const float* pw1     = (const float*)d_in[26];
    const float* pb1     = (const float*)d_in[27];
    const float* pw2     = (const float*)d_in[28];
    const float* pb2     = (const float*)d_in[29];
    const float* vw      = (const float*)d_in[30];
    const float* vb      = (const float*)d_in[31];

    const int* src = eidx;
    const int* dst = eidx + N_EDGES;

    float* fws = (float*)d_ws;
    size_t o = 0;
    float* bufA = fws + o; o += (size_t)N_NODES * 256;
    float* hhb  = fws + o; o += (size_t)N_NODES * 256;
    float* asb  = fws + o; o += (size_t)N_NODES * 4;
    float* adb  = fws + o; o += (size_t)N_NODES * 4;
    float* zreg = fws + o;            // ea_sum[4] psum[512] pcnt[8]
    float* ea_sum = zreg;
    float* psum   = zreg + 4;
    float* pcnt   = zreg + 516;
    o += 524;
    float* vtab = fws + o; o += 16;
    float* lpae = fws + o; o += 4;
    int* icnt = (int*)(fws + o);
    int* icur = icnt + N_NODES;
    int* irow = icur + N_NODES;          // N+1
    int* ieid = irow + N_NODES + 4;      // E
    int* csr_src = ieid + N_EDGES;       // E
    o += (size_t)(2 * N_NODES + N_NODES + 4 + 2 * N_EDGES);
    o = (o + 3) & ~(size_t)3;            // 16B align for float4
    float* csr_ea = fws + o; o += (size_t)N_EDGES * 4;

    hipMemsetAsync(zreg, 0, 524 * sizeof(float), stream);
    hipMemsetAsync(icnt, 0, 2 * N_NODES * sizeof(int), stream);

    ea_sum_kernel<<<256, 256, 0, stream>>>(ea, ea_sum);
    encoder_kernel<<<N_NODES / 8, 128, 0, stream>>>(x, enc_w1, enc_b1, enc_w2, enc_b2, bufA);
    count_kernel<<<(N_EDGES + 255) / 256, 256, 0, stream>>>(dst, icnt);
    scan_kernel<<<1, 1024, 0, stream>>>(icnt, irow);
    scatter_kernel<<<(N_EDGES + 255) / 256, 256, 0, stream>>>(dst, irow, icur, ieid);
    csr_gather_kernel<<<(N_EDGES + 255) / 256, 256, 0, stream>>>(src, ea, ieid, csr_src, csr_ea);

    // layer 1: K=128 -> HC=256, H=4, ELU
    vtab_kernel<4><<<1, 64, 0, stream>>>(g1_we, g1_ae, ea_sum, vtab, lpae);
    gemm2_kernel<256, 128, 4><<<dim3(N_NODES / 32, 2), 256, 0, stream>>>(bufA, g1_w, g1_asrc, g1_adst, hhb, asb, adb, 128);
    agg3_kernel<4, 256, true><<<N_NODES / 4, 256, 0, stream>>>(hhb, asb, adb, vtab, lpae, csr_src, csr_ea, irow, g1_b, bufA);

    // layer 2: K=256 -> HC=256, H=4, ELU
    vtab_kernel<4><<<1, 64, 0, stream>>>(g2_we, g2_ae, ea_sum, vtab, lpae);
    gemm2_kernel<256, 128, 4><<<dim3(N_NODES / 32, 2), 256, 0, stream>>>(bufA, g2_w, g2_asrc, g2_adst, hhb, asb, adb, 256);
    agg3_kernel<4, 256, true><<<N_NODES / 4, 256, 0, stream>>>(hhb, asb, adb, vtab, lpae, csr_src, csr_ea, irow, g2_b, bufA);

    // layer 3: K=256 -> HC=64, H=1, no ELU
    vtab_kernel<1><<<1, 64, 0, stream>>>(g3_we, g3_ae, ea_sum, vtab, lpae);
    gemm2_kernel<64, 64, 1><<<dim3(N_NODES / 32, 1), 256, 0, stream>>>(bufA, g3_w, g3_asrc, g3_adst, hhb, asb, adb, 256);
    agg3_kernel<1, 64, false><<<N_NODES / 4, 256, 0, stream>>>(hhb, asb, adb, vtab, lpae, csr_src, csr_ea, irow, g3_b, bufA);

    pool_kernel<<<(N_NODES + 63) / 64, 256, 0, stream>>>(bufA, batch, psum, pcnt);
    head_sf_kernel<<<dim3(6, 8), 128, 0, stream>>>(psum, pcnt, pw1, pb1, pw2, pb2, (float*)d_out);
    scores_kernel<<<8, 256, 0, stream>>>((float*)d_out, vw, vb, (float*)d_out);
}

// Round 4
// 337.253 us; speedup vs baseline: 1.8458x; 1.3287x over previous
//
#include <hip/hip_runtime.h>
#include <hip/hip_bf16.h>
#include <hip/hip_fp16.h>
#include <math.h>

#define N_NODES 20000
#define M_PAD 20096   // 314 * 64
#define N_EDGES 320000
#define N_GRAPHS 8

typedef _Float16 half8 __attribute__((ext_vector_type(8)));
typedef float floatx4 __attribute__((ext_vector_type(4)));

__device__ __forceinline__ float leaky02(float x) { return x > 0.f ? x : 0.2f * x; }
__device__ __forceinline__ float sel4(int hl, float a, float b, float c, float d) {
    return hl < 2 ? (hl == 0 ? a : b) : (hl == 2 ? c : d);
}

// ---------------- encoder: x[N,5] -> relu -> [N,64] -> relu -> [N,128] (fp16 out) --------
__global__ void encoder_kernel(const float* __restrict__ x,
                               const float* __restrict__ w1, const float* __restrict__ b1,
                               const float* __restrict__ w2, const float* __restrict__ b2,
                               __half* __restrict__ out) {
    const int n0 = blockIdx.x * 8;
    const int tid = threadIdx.x; // 128
    __shared__ float s_x[8][5];
    __shared__ float s_h1[8][64];
    if (tid < 40) s_x[tid / 5][tid % 5] = x[(size_t)(n0 + tid / 5) * 5 + (tid % 5)];
    __syncthreads();
    if (tid < 64) {
        #pragma unroll
        for (int n = 0; n < 8; ++n) {
            float a = b1[tid];
            #pragma unroll
            for (int k = 0; k < 5; ++k) a += s_x[n][k] * w1[k * 64 + tid];
            s_h1[n][tid] = fmaxf(a, 0.f);
        }
    }
    __syncthreads();
    float acc[8];
    #pragma unroll
    for (int n = 0; n < 8; ++n) acc[n] = b2[tid];
    for (int k = 0; k < 64; ++k) {
        float wv = w2[k * 128 + tid];
        #pragma unroll
        for (int n = 0; n < 8; ++n) acc[n] += s_h1[n][k] * wv;
    }
    #pragma unroll
    for (int n = 0; n < 8; ++n)
        out[(size_t)(n0 + n) * 128 + tid] = __float2half(fmaxf(acc[n], 0.f));
}

// ---------------- edge_attr mean (sum; divided later) ----------------
__global__ void ea_sum_kernel(const float* __restrict__ ea, float* __restrict__ ea_sum) {
    const int tid = threadIdx.x;
    float a0 = 0, a1 = 0, a2 = 0, a3 = 0;
    for (int i = blockIdx.x * blockDim.x + tid; i < N_EDGES; i += gridDim.x * blockDim.x) {
        float4 v = ((const float4*)ea)[i];
        a0 += v.x; a1 += v.y; a2 += v.z; a3 += v.w;
    }
    #pragma unroll
    for (int off = 32; off; off >>= 1) {
        a0 += __shfl_down(a0, off, 64);
        a1 += __shfl_down(a1, off, 64);
        a2 += __shfl_down(a2, off, 64);
        a3 += __shfl_down(a3, off, 64);
    }
    __shared__ float s[4][4];
    const int wave = tid >> 6, lane = tid & 63;
    if (lane == 0) { s[wave][0] = a0; s[wave][1] = a1; s[wave][2] = a2; s[wave][3] = a3; }
    __syncthreads();
    if (tid < 4) {
        float t = s[0][tid] + s[1][tid] + s[2][tid] + s[3][tid];
        atomicAdd(&ea_sum[tid], t);
    }
}

// ---------------- CSR by dst ----------------
__global__ void count_kernel(const int* __restrict__ dst, int* __restrict__ cnt) {
    int i = blockIdx.x * 256 + threadIdx.x;
    if (i < N_EDGES) atomicAdd(&cnt[dst[i]], 1);
}

__global__ void scan_kernel(const int* __restrict__ cnt, int* __restrict__ row_ptr) {
    __shared__ int s_sum[1024];
    const int tid = threadIdx.x;
    int local[20];
    int run = 0;
    const int base = tid * 20;
    #pragma unroll
    for (int i = 0; i < 20; ++i) {
        int idx = base + i;
        int v = (idx < N_NODES) ? cnt[idx] : 0;
        run += v;
        local[i] = run;
    }
    s_sum[tid] = run;
    __syncthreads();
    for (int off = 1; off < 1024; off <<= 1) {
        int v = (tid >= off) ? s_sum[tid - off] : 0;
        __syncthreads();
        s_sum[tid] += v;
        __syncthreads();
    }
    const int prev = (tid > 0) ? s_sum[tid - 1] : 0;
    #pragma unroll
    for (int i = 0; i < 20; ++i) {
        int idx = base + i;
        if (idx < N_NODES) row_ptr[idx + 1] = prev + local[i];
    }
    if (tid == 0) row_ptr[0] = 0;
}

__global__ void scatter_kernel(const int* __restrict__ dst, const int* __restrict__ row_ptr,
                               int* __restrict__ cur, int* __restrict__ eid) {
    int i = blockIdx.x * 256 + threadIdx.x;
    if (i < N_EDGES) {
        int d = dst[i];
        int p = atomicAdd(&cur[d], 1);
        eid[row_ptr[d] + p] = i;
    }
}

__global__ void csr_gather_kernel(const int* __restrict__ srcs, const float* __restrict__ ea,
                                  const int* __restrict__ eids,
                                  int* __restrict__ csr_src, float* __restrict__ csr_ea) {
    int e = blockIdx.x * 256 + threadIdx.x;
    if (e < N_EDGES) {
        int ei = eids[e];
        csr_src[e] = srcs[ei];
        ((float4*)csr_ea)[e] = ((const float4*)ea)[ei];
    }
}

// ---------------- weight convert+transpose: Wt[n][k] = (f16) W[k][n] ----------------
__global__ void wconv_kernel(const float* __restrict__ W, __half* __restrict__ Wt,
                             int K, int N) {
    int i = blockIdx.x * 256 + threadIdx.x;
    if (i < K * N) {
        int k = i / N, n = i % N;
        Wt[(size_t)n * K + k] = __float2half(W[i]);
    }
}

// ---------------- per-layer tiny precompute: v[k][h], loop a_e ----------------
template<int H>
__global__ void vtab_kernel(const float* __restrict__ We, const float* __restrict__ att_edge,
                            const float* __restrict__ ea_sum,
                            float* __restrict__ vtab, float* __restrict__ lpae) {
    const int tid = threadIdx.x;
    __shared__ float s_v[4][4];
    if (tid < 4 * H) {
        const int k = tid / H, h = tid % H;
        float v = 0.f;
        for (int c = 0; c < 64; ++c) v += We[k * (H * 64) + h * 64 + c] * att_edge[h * 64 + c];
        vtab[k * 4 + h] = v;
        s_v[k][h] = v;
    }
    __syncthreads();
    if (tid < H) {
        const float inv = 1.0f / (float)N_EDGES;
        float l = 0.f;
        #pragma unroll
        for (int k = 0; k < 4; ++k) l += ea_sum[k] * inv * s_v[k][tid];
        lpae[tid] = l;
    }
}

// ---------------- MFMA GEMM + fused attention scalars ----------------
// Y[M,N](f16) = X[M,K](f16) @ Wt[N,K]^T(f16), fp32 accum.
// Block: 64 rows x 64 cols, 4 waves (wave = 16 rows x 64 cols, 4 accum tiles).
// a_s[node, by] = sum over this block's 64 cols (BN=64 == one head, complete).
template<int N, int H>
__global__ __launch_bounds__(256) void mgemm_kernel(
    const __half* __restrict__ X, const __half* __restrict__ Wt,
    const float* __restrict__ asrc, const float* __restrict__ adst,
    __half* __restrict__ Y, float* __restrict__ a_s, float* __restrict__ a_d, int K) {
    constexpr int STR = 72; // f16 stride: 144B rows -> 16B-aligned b128, min-aliased banks
    __shared__ _Float16 sX[64 * STR];
    __shared__ _Float16 sW[64 * STR];
    const int tid = threadIdx.x;
    const int lane = tid & 63, w = tid >> 6;
    const int l16 = lane & 15, kg = lane >> 4;
    const int n0 = blockIdx.x * 64;
    const int c0 = blockIdx.y * 64;
    const int by = blockIdx.y;

    floatx4 acc[4];
    #pragma unroll
    for (int ct = 0; ct < 4; ++ct) acc[ct] = (floatx4){0.f, 0.f, 0.f, 0.f};

    const int srow = tid >> 2, sseg = tid & 3;
    for (int k0 = 0; k0 < K; k0 += 32) {
        float4 xv = *(const float4*)(X + (size_t)(n0 + srow) * K + k0 + sseg * 8);
        float4 wv = *(const float4*)(Wt + (size_t)(c0 + srow) * K + k0 + sseg * 8);
        __syncthreads();
        *(float4*)&sX[srow * STR + sseg * 8] = xv;
        *(float4*)&sW[srow * STR + sseg * 8] = wv;
        __syncthreads();
        half8 a = *(const half8*)&sX[(w * 16 + l16) * STR + kg * 8];
        #pragma unroll
        for (int ct = 0; ct < 4; ++ct) {
            half8 b = *(const half8*)&sW[(ct * 16 + l16) * STR + kg * 8];
            acc[ct] = __builtin_amdgcn_mfma_f32_16x16x32_f16(a, b, acc[ct], 0, 0, 0);
        }
    }

    // epilogue: C/D layout col = lane&15, row = (lane>>4)*4 + reg  [m89-verified]
    const int rowb = n0 + w * 16 + kg * 4;
    float ar[4], ad4[4];
    #pragma unroll
    for (int ct = 0; ct < 4; ++ct) {
        ar[ct] = asrc[c0 + ct * 16 + l16];
        ad4[ct] = adst[c0 + ct * 16 + l16];
    }
    #pragma unroll
    for (int ct = 0; ct < 4; ++ct) {
        const int col = c0 + ct * 16 + l16;
        #pragma unroll
        for (int r = 0; r < 4; ++r)
            Y[(size_t)(rowb + r) * N + col] = __float2half(acc[ct][r]);
    }
    #pragma unroll
    for (int r = 0; r < 4; ++r) {
        float p = acc[0][r] * ar[0] + acc[1][r] * ar[1] + acc[2][r] * ar[2] + acc[3][r] * ar[3];
        float q = acc[0][r] * ad4[0] + acc[1][r] * ad4[1] + acc[2][r] * ad4[2] + acc[3][r] * ad4[3];
        #pragma unroll
        for (int off = 1; off < 16; off <<= 1) {
            p += __shfl_xor(p, off, 64);
            q += __shfl_xor(q, off, 64);
        }
        if (l16 == 0) {
            const int node = rowb + r;
            a_s[(size_t)node * H + by] = p;
            a_d[(size_t)node * H + by] = q;
        }
    }
}

// ---------------- GAT aggregation: wave per node, online softmax, fp16 hh ----------------
template<int H, int HC, bool ELU>
__global__ __launch_bounds__(256) void agg3_kernel(
    const __half* __restrict__ hh,
    const float* __restrict__ a_s, const float* __restrict__ a_d,
    const float* __restrict__ vtab, const float* __restrict__ lpae,
    const int* __restrict__ csr_src, const float* __restrict__ csr_ea,
    const int* __restrict__ row_ptr, const float* __restrict__ bias,
    __half* __restrict__ out) {
    constexpr int CPT = HC / 64;
    const int wave = threadIdx.x >> 6;
    const int lane = threadIdx.x & 63;
    const int d = blockIdx.x * 4 + wave;

    const int base = row_ptr[d], end = row_ptr[d + 1];
    const int colbase = lane * CPT;
    const int hl = (H == 1) ? 0 : (colbase >> 6);

    float vt[4][H];
    #pragma unroll
    for (int k = 0; k < 4; ++k)
        #pragma unroll
        for (int h = 0; h < H; ++h) vt[k][h] = vtab[k * 4 + h];

    float add_[H];
    if (H == 4) {
        float4 t = *(const float4*)&a_d[(size_t)d * 4];
        add_[0] = t.x; add_[1] = t.y; add_[2] = t.z; add_[3] = t.w;
    } else {
        add_[0] = a_d[d];
    }
    float asd_h;
    if (H == 4) asd_h = a_s[(size_t)d * 4 + hl];
    else asd_h = a_s[d];

    float mh = leaky02(asd_h + add_[hl] + lpae[hl]);
    float zacc = 1.f;
    float acc[CPT];
    {
        const __half2* hp = (const __half2*)(hh + (size_t)d * HC + colbase);
        if (CPT == 4) {
            float2 f0 = __half22float2(hp[0]);
            float2 f1 = __half22float2(hp[1]);
            acc[0] = f0.x; acc[1] = f0.y; acc[2] = f1.x; acc[3] = f1.y;
        } else {
            acc[0] = __half2float(hh[(size_t)d * HC + colbase]);
        }
    }

#define EDGE_STEP(tt) { \
        int s_ = __shfl(my_s, (tt), 64); \
        float lt; \
        if (H == 4) { \
            float t0 = __shfl(l0, (tt), 64), t1 = __shfl(l1, (tt), 64); \
            float t2 = __shfl(l2, (tt), 64), t3 = __shfl(l3, (tt), 64); \
            lt = sel4(hl, t0, t1, t2, t3); \
        } else { \
            lt = __shfl(l0, (tt), 64); \
        } \
        float w_ = __expf(lt - mh); \
        const __half2* hp_ = (const __half2*)(hh + (size_t)s_ * HC + colbase); \
        if (CPT == 4) { \
            float2 f0_ = __half22float2(hp_[0]); \
            float2 f1_ = __half22float2(hp_[1]); \
            acc[0] += w_ * f0_.x; acc[1] += w_ * f0_.y; \
            acc[2] += w_ * f1_.x; acc[3] += w_ * f1_.y; \
        } else { \
            acc[0] += w_ * __half2float(hh[(size_t)s_ * HC + colbase]); \
        } \
        zacc += w_; }

    for (int c0 = base; c0 < end; c0 += 64) {
        const int nc = min(64, end - c0);
        int my_s = 0;
        float l0 = -1e30f, l1 = -1e30f, l2 = -1e30f, l3 = -1e30f;
        if (lane < nc) {
            my_s = csr_src[c0 + lane];
            float4 eav = ((const float4*)csr_ea)[c0 + lane];
            if (H == 4) {
                float4 as4 = *(const float4*)&a_s[(size_t)my_s * 4];
                l0 = leaky02(as4.x + add_[0] + eav.x * vt[0][0] + eav.y * vt[1][0] + eav.z * vt[2][0] + eav.w * vt[3][0]);
                l1 = leaky02(as4.y + add_[1] + eav.x * vt[0][1] + eav.y * vt[1][1] + eav.z * vt[2][1] + eav.w * vt[3][1]);
                l2 = leaky02(as4.z + add_[2] + eav.x * vt[0][2] + eav.y * vt[1][2] + eav.z * vt[2][2] + eav.w * vt[3][2]);
                l3 = leaky02(as4.w + add_[3] + eav.x * vt[0][3] + eav.y * vt[1][3] + eav.z * vt[2][3] + eav.w * vt[3][3]);
            } else {
                l0 = leaky02(a_s[my_s] + add_[0] + eav.x * vt[0][0] + eav.y * vt[1][0] + eav.z * vt[2][0] + eav.w * vt[3][0]);
            }
        }
        float cm0 = l0, cm1 = l1, cm2 = l2, cm3 = l3;
        #pragma unroll
        for (int off = 1; off < 64; off <<= 1) {
            cm0 = fmaxf(cm0, __shfl_xor(cm0, off, 64));
            if (H == 4) {
                cm1 = fmaxf(cm1, __shfl_xor(cm1, off, 64));
                cm2 = fmaxf(cm2, __shfl_xor(cm2, off, 64));
                cm3 = fmaxf(cm3, __shfl_xor(cm3, off, 64));
            }
        }
        float cmh = (H == 4) ? sel4(hl, cm0, cm1, cm2, cm3) : cm0;
        float newm = fmaxf(mh, cmh);
        float sc = __expf(mh - newm);
        zacc *= sc;
        #pragma unroll
        for (int c = 0; c < CPT; ++c) acc[c] *= sc;
        mh = newm;

        int t = 0;
        for (; t + 4 <= nc; t += 4) {
            EDGE_STEP(t)
            EDGE_STEP(t + 1)
            EDGE_STEP(t + 2)
            EDGE_STEP(t + 3)
        }
        for (; t < nc; ++t) {
            EDGE_STEP(t)
        }
    }
#undef EDGE_STEP

    const float invz = 1.f / (zacc + 1e-16f);
    #pragma unroll
    for (int c = 0; c < CPT; ++c) {
        float v = acc[c] * invz + bias[colbase + c];
        if (ELU) v = (v > 0.f) ? v : (__expf(v) - 1.f);
        acc[c] = v;
    }
    if (CPT == 4) {
        __half2* op = (__half2*)(out + (size_t)d * HC + colbase);
        op[0] = __floats2half2_rn(acc[0], acc[1]);
        op[1] = __floats2half2_rn(acc[2], acc[3]);
    } else {
        out[(size_t)d * HC + colbase] = __float2half(acc[0]);
    }
}

// ---------------- global mean pool (hierarchical, fp16 in) ----------------
__global__ void pool_kernel(const __half* __restrict__ h3, const int* __restrict__ batch,
                            float* __restrict__ psum, float* __restrict__ pcnt) {
    __shared__ float s_acc[8][64];
    __shared__ float s_cnt[8];
    const int tid = threadIdx.x; // 256
    for (int i = tid; i < 512; i += 256) s_acc[i >> 6][i & 63] = 0.f;
    if (tid < 8) s_cnt[tid] = 0.f;
    __syncthreads();
    const int col = tid & 63, nl = tid >> 6;
    const int n0 = blockIdx.x * 64;
    for (int nn = nl; nn < 64; nn += 4) {
        int n = n0 + nn;
        if (n < N_NODES) {
            int b = batch[n];
            atomicAdd(&s_acc[b][col], __half2float(h3[(size_t)n * 64 + col]));
            if (col == 0) atomicAdd(&s_cnt[b], 1.0f);
        }
    }
    __syncthreads();
    for (int i = tid; i < 512; i += 256) {
        float v = s_acc[i >> 6][i & 63];
        if (v != 0.f) atomicAdd(&psum[i], v);
    }
    if (tid < 8 && s_cnt[tid] > 0.f) atomicAdd(&pcnt[tid], s_cnt[tid]);
}

// ---------------- head part 1: static_features ----------------
__global__ void head_sf_kernel(const float* __restrict__ psum, const float* __restrict__ pcnt,
                               const float* __restrict__ w1, const float* __restrict__ b1,
                               const float* __restrict__ w2, const float* __restrict__ b2,
                               float* __restrict__ out) {
    const int b = blockIdx.y;
    const int c0 = blockIdx.x * 128;
    const int tid = threadIdx.x; // 128
    __shared__ float s_g[64];
    __shared__ float s_p1[128];
    if (tid < 64) {
        float c = pcnt[b];
        c = (c < 1.f) ? 1.f : c;
        s_g[tid] = psum[b * 64 + tid] / c;
    }
    __syncthreads();
    {
        float a = b1[tid];
        #pragma unroll 8
        for (int k = 0; k < 64; ++k) a += s_g[k] * w1[k * 128 + tid];
        s_p1[tid] = fmaxf(a, 0.f);
    }
    __syncthreads();
    const int col = c0 + tid;
    float a = b2[col];
    #pragma unroll 8
    for (int k = 0; k < 128; ++k) a += s_p1[k] * w2[k * 768 + col];
    out[b * 768 + col] = a;
}

// ---------------- head part 2: vulnerability scores ----------------
__global__ void scores_kernel(const float* __restrict__ sf,
                              const float* __restrict__ vw, const float* __restrict__ vb,
                              float* __restrict__ out) {
    const int b = blockIdx.x;
    const int tid = threadIdx.x; // 256
    const int wave = tid >> 6, lane = tid & 63;
    float part[5] = {0.f, 0.f, 0.f, 0.f, 0.f};
    for (int k = tid; k < 768; k += 256) {
        float s = sf[b * 768 + k];
        #pragma unroll
        for (int v = 0; v < 5; ++v) part[v] += s * vw[k * 5 + v];
    }
    #pragma unroll
    for (int v = 0; v < 5; ++v)
        #pragma unroll
        for (int off = 32; off; off >>= 1) part[v] += __shfl_down(part[v], off, 64);
    __shared__ float sred[4][5];
    if (lane == 0) {
        #pragma unroll
        for (int v = 0; v < 5; ++v) sred[wave][v] = part[v];
    }
    __syncthreads();
    if (tid < 5) {
        float a = vb[tid] + sred[0][tid] + sred[1][tid] + sred[2][tid] + sred[3][tid];
        out[6144 + b * 5 + tid] = 1.f / (1.f + __expf(-a));
    }
}

extern "C" void kernel_launch(void* const* d_in, const int* in_sizes, int n_in,
                              void* d_out, int out_size, void* d_ws, size_t ws_size,
                              hipStream_t stream) {
    const float* x       = (const float*)d_in[0];
    const int*   eidx    = (const int*)d_in[1];
    const float* ea      = (const float*)d_in[2];
    const int*   batch   = (const int*)d_in[3];
    const float* enc_w1  = (const float*)d_in[4];
    const float* enc_b1  = (const float*)d_in[5];
    const float* enc_w2  = (const float*)d_in[6];
    const float* enc_b2  = (const float*)d_in[7];
    const float* g1_w    = (const float*)d_in[8];
    const float* g1_asrc = (const float*)d_in[9];
    const float* g1_adst = (const float*)d_in[10];
    const float* g1_we   = (const float*)d_in[11];
    const float* g1_ae   = (const float*)d_in[12];
    const float* g1_b    = (const float*)d_in[13];
    const float* g2_w    = (const float*)d_in[14];
    const float* g2_asrc = (const float*)d_in[15];
    const float* g2_adst = (const float*)d_in[16];
    const float* g2_we   = (const float*)d_in[17];
    const float* g2_ae   = (const float*)d_in[18];
    const float* g2_b    = (const float*)d_in[19];
    const float* g3_w    = (const float*)d_in[20];
    const float* g3_asrc = (const float*)d_in[21];
    const float* g3_adst = (const float*)d_in[22];
    const float* g3_we   = (const float*)d_in[23];
    const float* g3_ae   = (const float*)d_in[24];
    const float* g3_b    = (const float*)d_in[25];
    const float* pw1     = (const float*)d_in[26];
    const float* pb1     = (const float*)d_in[27];
    const float* pw2     = (const float*)d_in[28];
    const float* pb2     = (const float*)d_in[29];
    const float* vw      = (const float*)d_in[30];
    const float* vb      = (const float*)d_in[31];

    const int* src = eidx;
    const int* dst = eidx + N_EDGES;

    // ---- workspace layout (all node-row buffers padded to M_PAD rows) ----
    __half* h16a = (__half*)d_ws;                           // [M_PAD][256] f16
    __half* h16b = h16a + (size_t)M_PAD * 256;              // [M_PAD][256] f16
    __half* hh16 = h16b + (size_t)M_PAD * 256;              // [M_PAD][256] f16
    __half* wt16 = hh16 + (size_t)M_PAD * 256;              // [256][256] f16
    float* asb   = (float*)(wt16 + 256 * 256);              // [M_PAD][4]
    float* adb   = asb + (size_t)M_PAD * 4;                 // [M_PAD][4]
    float* zreg  = adb + (size_t)M_PAD * 4;                 // ea_sum[4] psum[512] pcnt[8]
    float* ea_sum = zreg;
    float* psum   = zreg + 4;
    float* pcnt   = zreg + 516;
    float* vtab  = zreg + 524;
    float* lpae  = vtab + 16;
    int* icnt    = (int*)(lpae + 4);
    int* icur    = icnt + N_NODES;
    int* irow    = icur + N_NODES;       // N+1
    int* ieid    = irow + N_NODES + 4;   // E
    int* csr_src = ieid + N_EDGES;       // E
    float* csr_ea = (float*)(csr_src + N_EDGES);  // E*4, 16B-aligned by construction

    hipMemsetAsync(zreg, 0, 544 * sizeof(float), stream);
    hipMemsetAsync(icnt, 0, 2 * N_NODES * sizeof(int), stream);

    ea_sum_kernel<<<256, 256, 0, stream>>>(ea, ea_sum);
    encoder_kernel<<<N_NODES / 8, 128, 0, stream>>>(x, enc_w1, enc_b1, enc_w2, enc_b2, h16a);
    count_kernel<<<(N_EDGES + 255) / 256, 256, 0, stream>>>(dst, icnt);
    scan_kernel<<<1, 1024, 0, stream>>>(icnt, irow);
    scatter_kernel<<<(N_EDGES + 255) / 256, 256, 0, stream>>>(dst, irow, icur, ieid);
    csr_gather_kernel<<<(N_EDGES + 255) / 256, 256, 0, stream>>>(src, ea, ieid, csr_src, csr_ea);

    // layer 1: K=128 -> HC=256, H=4, ELU      (h16a -> hh16 -> h16b)
    wconv_kernel<<<(128 * 256 + 255) / 256, 256, 0, stream>>>(g1_w, wt16, 128, 256);
    vtab_kernel<4><<<1, 64, 0, stream>>>(g1_we, g1_ae, ea_sum, vtab, lpae);
    mgemm_kernel<256, 4><<<dim3(M_PAD / 64, 4), 256, 0, stream>>>(h16a, wt16, g1_asrc, g1_adst, hh16, asb, adb, 128);
    agg3_kernel<4, 256, true><<<N_NODES / 4, 256, 0, stream>>>(hh16, asb, adb, vtab, lpae, csr_src, csr_ea, irow, g1_b, h16b);

    // layer 2: K=256 -> HC=256, H=4, ELU      (h16b -> hh16 -> h16a)
    wconv_kernel<<<(256 * 256 + 255) / 256, 256, 0, stream>>>(g2_w, wt16, 256, 256);
    vtab_kernel<4><<<1, 64, 0, stream>>>(g2_we, g2_ae, ea_sum, vtab, lpae);
    mgemm_kernel<256, 4><<<dim3(M_PAD / 64, 4), 256, 0, stream>>>(h16b, wt16, g2_asrc, g2_adst, hh16, asb, adb, 256);
    agg3_kernel<4, 256, true><<<N_NODES / 4, 256, 0, stream>>>(hh16, asb, adb, vtab, lpae, csr_src, csr_ea, irow, g2_b, h16a);

    // layer 3: K=256 -> HC=64, H=1, no ELU    (h16a -> hh16 -> h16b)
    wconv_kernel<<<(256 * 64 + 255) / 256, 256, 0, stream>>>(g3_w, wt16, 256, 64);
    vtab_kernel<1><<<1, 64, 0, stream>>>(g3_we, g3_ae, ea_sum, vtab, lpae);
    mgemm_kernel<64, 1><<<dim3(M_PAD / 64, 1), 256, 0, stream>>>(h16a, wt16, g3_asrc, g3_adst, hh16, asb, adb, 256);
    agg3_kernel<1, 64, false><<<N_NODES / 4, 256, 0, stream>>>(hh16, asb, adb, vtab, lpae, csr_src, csr_ea, irow, g3_b, h16b);

    pool_kernel<<<(N_NODES + 63) / 64, 256, 0, stream>>>(h16b, batch, psum, pcnt);
    head_sf_kernel<<<dim3(6, 8), 128, 0, stream>>>(psum, pcnt, pw1, pb1, pw2, pb2, (float*)d_out);
    scores_kernel<<<8, 256, 0, stream>>>((float*)d_out, vw, vb, (float*)d_out);
}